// Round 6
// baseline (335.099 us; speedup 1.0000x reference)
//
#include <hip/hip_runtime.h>
#include <math.h>

#define NN 100000
#define EE 600000
#define DD 128
#define GG 256
#define EPSV 1e-5f

typedef __attribute__((ext_vector_type(8))) __bf16 bf16x8;
typedef __attribute__((ext_vector_type(16))) float f32x16;
typedef __attribute__((ext_vector_type(4))) unsigned short us4;

// ---------------- workspace layout (bytes) ----------------
// A1/B1 double as Sg/Qg for norm1 (finalize converts in place); same for A2/B2.
#define OFF_A1      0
#define OFF_B1      131072
#define OFF_A2      262144
#define OFF_B2      393216
#define OFF_DEG     524288      // N ints -> ends 924,288  (memset 0..924288 covers A/B/deg)
#define OFF_ROWPTR  924288      // N+1 ints
#define OFF_CURSOR  1324352     // N ints
#define OFF_BSUMS   1724352     // <=512 ints
#define OFF_BOFFS   1726400     // <=512 ints (unused)
#define OFF_ELIST   1728448     // E ints  -> ends 4,128,448
#define OFF_WB      4128448     // 128*256 bf16 = 65,536 -> ends 4,193,984
#define OFF_H1B     4193984     // N*128 bf16 = 25,600,000
#define WS_NEED_A   (OFF_H1B + 25600000ULL)

__device__ __forceinline__ int lower_bound_i(const int* __restrict__ a, int n, int v) {
    int lo = 0, hi = n;
    while (lo < hi) { int mid = (lo + hi) >> 1; if (a[mid] < v) lo = mid + 1; else hi = mid; }
    return lo;
}

__device__ __forceinline__ unsigned short f2bf(float f) {
    unsigned int u = __float_as_uint(f);
    unsigned int r = u + 0x7fffu + ((u >> 16) & 1u);
    return (unsigned short)(r >> 16);
}

// ---------------- stats phase 1: full-grid partial sums into Sg/Qg (atomics) ----------------
// 128 rows per block; batch sorted -> block spans 1..3 graph segments.
__global__ __launch_bounds__(256) void stats_p1(
    const float* __restrict__ X, const int* __restrict__ batch,
    float* __restrict__ Sg, float* __restrict__ Qg)
{
    int t = threadIdx.x;
    int rl = t >> 5, fq = t & 31;
    int r0 = blockIdx.x * 128;
    int rend = r0 + 128; if (rend > NN) rend = NN;
    __shared__ float ls[8 * 128];
    __shared__ float lq[8 * 128];
    int g0 = batch[r0], g1 = batch[rend - 1];
    const float4* X4 = (const float4*)X;
    for (int g = g0; g <= g1; ++g) {
        int sa = (g == g0) ? r0   : lower_bound_i(batch, NN, g);
        int sb = (g == g1) ? rend : lower_bound_i(batch, NN, g + 1);
        float s0 = 0.f, s1 = 0.f, s2 = 0.f, s3 = 0.f;
        float q0 = 0.f, q1 = 0.f, q2 = 0.f, q3 = 0.f;
        for (int r = sa + rl; r < sb; r += 8) {
            float4 v = X4[r * 32 + fq];
            s0 += v.x; s1 += v.y; s2 += v.z; s3 += v.w;
            q0 += v.x * v.x; q1 += v.y * v.y; q2 += v.z * v.z; q3 += v.w * v.w;
        }
        ls[rl * 128 + fq * 4 + 0] = s0; ls[rl * 128 + fq * 4 + 1] = s1;
        ls[rl * 128 + fq * 4 + 2] = s2; ls[rl * 128 + fq * 4 + 3] = s3;
        lq[rl * 128 + fq * 4 + 0] = q0; lq[rl * 128 + fq * 4 + 1] = q1;
        lq[rl * 128 + fq * 4 + 2] = q2; lq[rl * 128 + fq * 4 + 3] = q3;
        __syncthreads();
        if (t < 32) {
            #pragma unroll
            for (int k = 0; k < 4; k++) {
                float as = 0.f, aq = 0.f;
                #pragma unroll
                for (int j = 0; j < 8; j++) { as += ls[j * 128 + t * 4 + k]; aq += lq[j * 128 + t * 4 + k]; }
                atomicAdd(&Sg[g * DD + t * 4 + k], as);
                atomicAdd(&Qg[g * DD + t * 4 + k], aq);
            }
        }
        __syncthreads();
    }
}

// ---------------- finalize: Sg/Qg -> A/B in place; blocks GG/GG+1 convert weights ----------------
__global__ __launch_bounds__(128) void finalize_kernel(
    const int* __restrict__ batch, float* S, float* Q,
    const float* __restrict__ w, const float* __restrict__ bb, const float* __restrict__ ms,
    unsigned short* __restrict__ wb, const float* __restrict__ wl, const float* __restrict__ wr,
    int doW)
{
    int g = blockIdx.x;
    if (g >= GG) {
        if (!doW) return;
        const float* W = (g == GG) ? wl : wr;
        int kofs = (g == GG) ? 0 : 128;
        for (int tt = threadIdx.x; tt < DD * 32; tt += 128) {
            int j = tt >> 5, k4 = tt & 31;
            float4 v = ((const float4*)W)[j * 32 + k4];
            us4 o = { f2bf(v.x), f2bf(v.y), f2bf(v.z), f2bf(v.w) };
            *(us4*)&wb[j * 256 + kofs + k4 * 4] = o;
        }
        return;
    }
    __shared__ int sh[2];
    if (threadIdx.x == 0) { sh[0] = lower_bound_i(batch, NN, g); sh[1] = lower_bound_i(batch, NN, g + 1); }
    __syncthreads();
    int cnt = sh[1] - sh[0];
    float c = (float)(cnt > 0 ? cnt : 1);
    float inv_c = 1.0f / c;
    int d = threadIdx.x;
    float m  = S[g * DD + d] * inv_c;
    float qm = Q[g * DD + d] * inv_c;
    float sc = ms[d];
    float var = qm - m * m * sc * (2.0f - sc);
    float Ad = w[d] * rsqrtf(var + EPSV);
    S[g * DD + d] = Ad;
    Q[g * DD + d] = bb[d] - Ad * m * sc;
}

// ---------------- h1b = bf16(A1*x + B1), full grid ----------------
__global__ __launch_bounds__(256) void h1b_kernel(
    const float* __restrict__ X, const int* __restrict__ batch,
    const float* __restrict__ A1, const float* __restrict__ B1, unsigned short* __restrict__ h1b)
{
    int f = blockIdx.x * 256 + threadIdx.x;
    if (f >= NN * 32) return;
    int i = f >> 5, c = f & 31;
    int g = batch[i];
    float4 v = ((const float4*)X)[f];
    float4 a = ((const float4*)A1)[g * 32 + c];
    float4 b = ((const float4*)B1)[g * 32 + c];
    us4 o = { f2bf(fmaf(a.x, v.x, b.x)), f2bf(fmaf(a.y, v.y, b.y)),
              f2bf(fmaf(a.z, v.z, b.z)), f2bf(fmaf(a.w, v.w, b.w)) };
    *(us4*)&h1b[i * DD + c * 4] = o;
}

// ---------------- norm2 apply in place on d_out, full grid ----------------
__global__ __launch_bounds__(256) void apply_kernel(float* __restrict__ H, const int* __restrict__ batch,
                                                    const float* __restrict__ A2, const float* __restrict__ B2) {
    int f = blockIdx.x * 256 + threadIdx.x;
    if (f >= NN * 32) return;
    int i = f >> 5, c = f & 31;
    int g = batch[i];
    float4 v = ((float4*)H)[f];
    float4 a = ((const float4*)A2)[g * 32 + c];
    float4 b = ((const float4*)B2)[g * 32 + c];
    v.x = fmaf(a.x, v.x, b.x); v.y = fmaf(a.y, v.y, b.y);
    v.z = fmaf(a.z, v.z, b.z); v.w = fmaf(a.w, v.w, b.w);
    ((float4*)H)[f] = v;
}

// ---------------- CSR build ----------------
__global__ __launch_bounds__(256) void deg_kernel(const int* __restrict__ dst, int* __restrict__ deg) {
    int e = blockIdx.x * 256 + threadIdx.x;
    if (e < EE) atomicAdd(&deg[dst[e]], 1);
}

__global__ __launch_bounds__(256) void scan1(const int* __restrict__ deg, int* __restrict__ bsums) {
    int b = blockIdx.x, t = threadIdx.x;
    int base = b * 1024 + t * 4;
    int v = 0;
    #pragma unroll
    for (int k = 0; k < 4; k++) { int i = base + k; if (i < NN) v += deg[i]; }
    __shared__ int sd[256];
    sd[t] = v; __syncthreads();
    for (int off = 128; off > 0; off >>= 1) { if (t < off) sd[t] += sd[t + off]; __syncthreads(); }
    if (t == 0) bsums[b] = sd[0];
}

__global__ __launch_bounds__(256) void scan3(const int* __restrict__ deg, const int* __restrict__ bsums,
                                             int* __restrict__ rowptr, int* __restrict__ cursor) {
    int b = blockIdx.x, t = threadIdx.x;
    int boff = 0;
    for (int j = 0; j < b; j++) boff += bsums[j];
    int base = b * 1024 + t * 4;
    int d0 = 0, d1 = 0, d2 = 0, d3 = 0;
    if (base     < NN) d0 = deg[base];
    if (base + 1 < NN) d1 = deg[base + 1];
    if (base + 2 < NN) d2 = deg[base + 2];
    if (base + 3 < NN) d3 = deg[base + 3];
    int tsum = d0 + d1 + d2 + d3;
    __shared__ int sd[256];
    sd[t] = tsum; __syncthreads();
    for (int off = 1; off < 256; off <<= 1) {
        int a = (t >= off) ? sd[t - off] : 0;
        __syncthreads();
        sd[t] += a;
        __syncthreads();
    }
    int exc = sd[t] - tsum + boff;
    int p0 = exc, p1 = exc + d0, p2 = exc + d0 + d1, p3 = exc + d0 + d1 + d2;
    if (base     < NN) { rowptr[base]     = p0; cursor[base]     = p0; }
    if (base + 1 < NN) { rowptr[base + 1] = p1; cursor[base + 1] = p1; }
    if (base + 2 < NN) { rowptr[base + 2] = p2; cursor[base + 2] = p2; }
    if (base + 3 < NN) { rowptr[base + 3] = p3; cursor[base + 3] = p3; }
    if (b == 0 && t == 0) rowptr[NN] = EE;
}

__global__ __launch_bounds__(256) void fill_kernel(const int* __restrict__ src, const int* __restrict__ dst,
                                                   int* __restrict__ cursor, int* __restrict__ elist) {
    int e = blockIdx.x * 256 + threadIdx.x;
    if (e < EE) {
        int p = atomicAdd(&cursor[dst[e]], 1);
        elist[p] = src[e];
    }
}

// ---------------- agg (path A): wave per node, 8 edges / 4 gathers in flight ----------------
// writes bf16 agg row i into d_out at byte offset i*512.
__global__ __launch_bounds__(256) void agg_a(
    const unsigned short* __restrict__ h1b,
    const int* __restrict__ rowptr, const int* __restrict__ elist, float* __restrict__ out)
{
    int i = blockIdx.x * 4 + (threadIdx.x >> 6);
    if (i >= NN) return;
    int lane = threadIdx.x & 63;
    int half = lane >> 5, j = lane & 31;
    int beg = rowptr[i], end = rowptr[i + 1];
    float a0 = -INFINITY, a1 = -INFINITY, a2 = -INFINITY, a3 = -INFINITY;
    int last = end - 1;
    for (int e = beg; e < end; e += 8) {
        int e0 = e + half;
        int i0 = elist[e0 < last ? e0 : last];
        int i1 = elist[e0 + 2 < last ? e0 + 2 : last];
        int i2 = elist[e0 + 4 < last ? e0 + 4 : last];
        int i3 = elist[e0 + 6 < last ? e0 + 6 : last];
        us4 p0 = *(const us4*)(h1b + i0 * DD + j * 4);
        us4 p1 = *(const us4*)(h1b + i1 * DD + j * 4);
        us4 p2 = *(const us4*)(h1b + i2 * DD + j * 4);
        us4 p3 = *(const us4*)(h1b + i3 * DD + j * 4);
        #pragma unroll
        for (int k = 0; k < 1; k++) { } // keep loads adjacent
        a0 = fmaxf(a0, fmaxf(fmaxf(__uint_as_float((unsigned)p0[0] << 16), __uint_as_float((unsigned)p1[0] << 16)),
                             fmaxf(__uint_as_float((unsigned)p2[0] << 16), __uint_as_float((unsigned)p3[0] << 16))));
        a1 = fmaxf(a1, fmaxf(fmaxf(__uint_as_float((unsigned)p0[1] << 16), __uint_as_float((unsigned)p1[1] << 16)),
                             fmaxf(__uint_as_float((unsigned)p2[1] << 16), __uint_as_float((unsigned)p3[1] << 16))));
        a2 = fmaxf(a2, fmaxf(fmaxf(__uint_as_float((unsigned)p0[2] << 16), __uint_as_float((unsigned)p1[2] << 16)),
                             fmaxf(__uint_as_float((unsigned)p2[2] << 16), __uint_as_float((unsigned)p3[2] << 16))));
        a3 = fmaxf(a3, fmaxf(fmaxf(__uint_as_float((unsigned)p0[3] << 16), __uint_as_float((unsigned)p1[3] << 16)),
                             fmaxf(__uint_as_float((unsigned)p2[3] << 16), __uint_as_float((unsigned)p3[3] << 16))));
    }
    a0 = fmaxf(a0, __shfl_xor(a0, 32, 64));
    a1 = fmaxf(a1, __shfl_xor(a1, 32, 64));
    a2 = fmaxf(a2, __shfl_xor(a2, 32, 64));
    a3 = fmaxf(a3, __shfl_xor(a3, 32, 64));
    if (half == 0) {
        us4 r = { 0, 0, 0, 0 };
        if (end > beg) {
            r[0] = (unsigned short)(__float_as_uint(a0) >> 16);
            r[1] = (unsigned short)(__float_as_uint(a1) >> 16);
            r[2] = (unsigned short)(__float_as_uint(a2) >> 16);
            r[3] = (unsigned short)(__float_as_uint(a3) >> 16);
        }
        *(us4*)((unsigned short*)((char*)out + (size_t)i * 512) + j * 4) = r;
    }
}

// ---------------- gemm (path A): 64 rows/block, A-tile in LDS, B-frags from global wb ----------------
#define USTR 264
__global__ __launch_bounds__(256) void gemm_a(
    const float* __restrict__ X, const unsigned short* __restrict__ h1b,
    const unsigned short* __restrict__ wb, const float* __restrict__ blv,
    float* __restrict__ out)
{
    __shared__ unsigned short sU[64 * USTR];   // 33.8 KB
    int tid = threadIdx.x;
    int i0 = blockIdx.x * 64;

    for (int t = tid; t < 64 * 32; t += 256) {
        int r = t >> 5, c = t & 31;
        int i = i0 + r; if (i >= NN) i = NN - 1;
        uint4 v;
        if (c < 16) v = ((const uint4*)((const char*)out + (size_t)i * 512))[c];
        else        v = ((const uint4*)(h1b + (size_t)i * DD))[c - 16];
        *(uint4*)&sU[r * USTR + c * 8] = v;
    }
    __syncthreads();

    int lane = tid & 63, wave = tid >> 6;
    int m = lane & 31, hf = lane >> 5;
    int col = wave * 32 + m;
    const unsigned short* bcol = wb + col * 256 + hf * 8;

    f32x16 acc0, acc1;
    #pragma unroll
    for (int r = 0; r < 16; r++) { acc0[r] = 0.f; acc1[r] = 0.f; }

    #pragma unroll
    for (int h = 0; h < 2; h++) {
        bf16x8 bfr[8];
        #pragma unroll
        for (int s = 0; s < 8; s++) bfr[s] = *(const bf16x8*)(bcol + h * 128 + s * 16);
        #pragma unroll
        for (int s = 0; s < 8; s++) {
            int ko = h * 128 + s * 16 + hf * 8;
            bf16x8 a0 = *(const bf16x8*)&sU[m * USTR + ko];
            bf16x8 a1 = *(const bf16x8*)&sU[(32 + m) * USTR + ko];
            acc0 = __builtin_amdgcn_mfma_f32_32x32x16_bf16(a0, bfr[s], acc0, 0, 0, 0);
            acc1 = __builtin_amdgcn_mfma_f32_32x32x16_bf16(a1, bfr[s], acc1, 0, 0, 0);
        }
    }

    float blc = blv[col];
    #pragma unroll
    for (int reg = 0; reg < 16; reg++) {
        int rl = (reg & 3) + 8 * (reg >> 2) + 4 * hf;
        int ia = i0 + rl;
        int ib = i0 + 32 + rl;
        if (ia < NN) {
            float v = X[ia * DD + col] + blc + acc0[reg];
            out[ia * DD + col] = v > 0.f ? v : 0.f;
        }
        if (ib < NN) {
            float v = X[ib * DD + col] + blc + acc1[reg];
            out[ib * DD + col] = v > 0.f ? v : 0.f;
        }
    }
}

// ---------------- fallback path B: fp32 agg + LDS gemm ----------------
__global__ __launch_bounds__(256) void agg_b(
    const float* __restrict__ X, const int* __restrict__ batch,
    const float* __restrict__ A1, const float* __restrict__ B1,
    const int* __restrict__ rowptr, const int* __restrict__ elist, float* __restrict__ H)
{
    int i = blockIdx.x * 2 + (threadIdx.x >> 7);
    int d = threadIdx.x & 127;
    int beg = rowptr[i], end = rowptr[i + 1];
    float acc = -INFINITY;
    int e = beg;
    for (; e + 2 <= end; e += 2) {
        int s0 = elist[e], s1 = elist[e + 1];
        int g0 = batch[s0], g1 = batch[s1];
        float v0 = fmaf(A1[g0 * DD + d], X[s0 * DD + d], B1[g0 * DD + d]);
        float v1 = fmaf(A1[g1 * DD + d], X[s1 * DD + d], B1[g1 * DD + d]);
        acc = fmaxf(acc, fmaxf(v0, v1));
    }
    for (; e < end; e++) {
        int s = elist[e]; int g = batch[s];
        acc = fmaxf(acc, fmaf(A1[g * DD + d], X[s * DD + d], B1[g * DD + d]));
    }
    if (end == beg) acc = 0.f;
    H[i * DD + d] = acc;
}

#define BM 128
#define LDT 72
__global__ __launch_bounds__(256) void gemm_b(
    const float* __restrict__ X, const int* __restrict__ batch,
    const float* __restrict__ A1, const float* __restrict__ B1,
    const float* __restrict__ wl, const float* __restrict__ blv, const float* __restrict__ wr,
    float* __restrict__ H)
{
    __shared__ unsigned short Ut[BM * LDT];
    __shared__ unsigned short Wt[DD * LDT];
    int i0 = blockIdx.x * BM;
    int tid = threadIdx.x;
    int lane = tid & 63, wave = tid >> 6;
    int wrow = (wave >> 1) * 64, wcol = (wave & 1) * 64;
    int m = lane & 31, hf = lane >> 5;

    f32x16 acc00, acc01, acc10, acc11;
    #pragma unroll
    for (int r = 0; r < 16; r++) { acc00[r] = 0.f; acc01[r] = 0.f; acc10[r] = 0.f; acc11[r] = 0.f; }

    for (int c = 0; c < 4; c++) {
        __syncthreads();
        for (int t = tid; t < BM * 16; t += 256) {
            int r = t >> 4, c4 = t & 15;
            int i = i0 + r; if (i >= NN) i = NN - 1;
            float4 v;
            if (c < 2) {
                v = ((const float4*)H)[i * 32 + c * 16 + c4];
            } else {
                int g = batch[i];
                float4 xv = ((const float4*)X)[i * 32 + (c - 2) * 16 + c4];
                float4 a = ((const float4*)A1)[g * 32 + (c - 2) * 16 + c4];
                float4 b = ((const float4*)B1)[g * 32 + (c - 2) * 16 + c4];
                v.x = fmaf(a.x, xv.x, b.x); v.y = fmaf(a.y, xv.y, b.y);
                v.z = fmaf(a.z, xv.z, b.z); v.w = fmaf(a.w, xv.w, b.w);
            }
            us4 o = { f2bf(v.x), f2bf(v.y), f2bf(v.z), f2bf(v.w) };
            *(us4*)&Ut[r * LDT + c4 * 4] = o;
        }
        {
            const float* Wsrc = (c < 2) ? wl : wr;
            int kb = (c & 1) * 16;
            for (int t = tid; t < DD * 16; t += 256) {
                int j = t >> 4, c4 = t & 15;
                float4 v = ((const float4*)Wsrc)[j * 32 + kb + c4];
                us4 o = { f2bf(v.x), f2bf(v.y), f2bf(v.z), f2bf(v.w) };
                *(us4*)&Wt[j * LDT + c4 * 4] = o;
            }
        }
        __syncthreads();
        #pragma unroll
        for (int kk = 0; kk < 4; kk++) {
            int kb2 = kk * 16 + hf * 8;
            bf16x8 a0 = *(const bf16x8*)&Ut[(wrow      + m) * LDT + kb2];
            bf16x8 a1 = *(const bf16x8*)&Ut[(wrow + 32 + m) * LDT + kb2];
            bf16x8 b0 = *(const bf16x8*)&Wt[(wcol      + m) * LDT + kb2];
            bf16x8 b1 = *(const bf16x8*)&Wt[(wcol + 32 + m) * LDT + kb2];
            acc00 = __builtin_amdgcn_mfma_f32_32x32x16_bf16(a0, b0, acc00, 0, 0, 0);
            acc01 = __builtin_amdgcn_mfma_f32_32x32x16_bf16(a0, b1, acc01, 0, 0, 0);
            acc10 = __builtin_amdgcn_mfma_f32_32x32x16_bf16(a1, b0, acc10, 0, 0, 0);
            acc11 = __builtin_amdgcn_mfma_f32_32x32x16_bf16(a1, b1, acc11, 0, 0, 0);
        }
    }

    int col0 = wcol + m, col1 = wcol + 32 + m;
    float bl0 = blv[col0], bl1 = blv[col1];
    #pragma unroll
    for (int reg = 0; reg < 16; reg++) {
        int rl = (reg & 3) + 8 * (reg >> 2) + 4 * hf;
        int ia = i0 + wrow + rl;
        int ib = i0 + wrow + 32 + rl;
        if (ia < NN) {
            float v0 = X[ia * DD + col0] + bl0 + acc00[reg];
            float v1 = X[ia * DD + col1] + bl1 + acc01[reg];
            H[ia * DD + col0] = v0 > 0.f ? v0 : 0.f;
            H[ia * DD + col1] = v1 > 0.f ? v1 : 0.f;
        }
        if (ib < NN) {
            float v0 = X[ib * DD + col0] + bl0 + acc10[reg];
            float v1 = X[ib * DD + col1] + bl1 + acc11[reg];
            H[ib * DD + col0] = v0 > 0.f ? v0 : 0.f;
            H[ib * DD + col1] = v1 > 0.f ? v1 : 0.f;
        }
    }
}

extern "C" void kernel_launch(void* const* d_in, const int* in_sizes, int n_in,
                              void* d_out, int out_size, void* d_ws, size_t ws_size,
                              hipStream_t stream) {
    const float* x    = (const float*)d_in[0];
    const int*   ei   = (const int*)d_in[1];
    const int*   batch= (const int*)d_in[2];
    const float* n1w  = (const float*)d_in[3];
    const float* n1b  = (const float*)d_in[4];
    const float* n1ms = (const float*)d_in[5];
    const float* n2w  = (const float*)d_in[6];
    const float* n2b  = (const float*)d_in[7];
    const float* n2ms = (const float*)d_in[8];
    const float* wl   = (const float*)d_in[9];
    const float* bl   = (const float*)d_in[10];
    const float* wr   = (const float*)d_in[11];
    float* out = (float*)d_out;

    char* w = (char*)d_ws;
    float* A1     = (float*)(w + OFF_A1);     // doubles as Sg1
    float* B1     = (float*)(w + OFF_B1);     // doubles as Qg1
    float* A2     = (float*)(w + OFF_A2);     // doubles as Sg2
    float* B2     = (float*)(w + OFF_B2);     // doubles as Qg2
    int*   deg    = (int*)(w + OFF_DEG);
    int*   rowptr = (int*)(w + OFF_ROWPTR);
    int*   cursor = (int*)(w + OFF_CURSOR);
    int*   bsums  = (int*)(w + OFF_BSUMS);
    int*   elist  = (int*)(w + OFF_ELIST);
    unsigned short* wb  = (unsigned short*)(w + OFF_WB);
    unsigned short* h1b = (unsigned short*)(w + OFF_H1B);

    const int* src = ei;
    const int* dst = ei + EE;
    const int NB1024 = (NN + 1023) / 1024;
    const int NBROW  = (NN + 127) / 128;      // 782
    bool bigws = (ws_size >= WS_NEED_A);

    // zero A1/B1/A2/B2 (=Sg/Qg accumulators) and deg in one contiguous memset
    hipMemsetAsync(w, 0, OFF_ROWPTR, stream);

    // norm1 stats
    stats_p1<<<NBROW, 256, 0, stream>>>(x, batch, A1, B1);
    finalize_kernel<<<GG + 2, 128, 0, stream>>>(batch, A1, B1, n1w, n1b, n1ms,
                                                wb, wl, wr, bigws ? 1 : 0);
    if (bigws)
        h1b_kernel<<<(NN * 32 + 255) / 256, 256, 0, stream>>>(x, batch, A1, B1, h1b);

    // CSR
    deg_kernel<<<(EE + 255) / 256, 256, 0, stream>>>(dst, deg);
    scan1<<<NB1024, 256, 0, stream>>>(deg, bsums);
    scan3<<<NB1024, 256, 0, stream>>>(deg, bsums, rowptr, cursor);
    fill_kernel<<<(EE + 255) / 256, 256, 0, stream>>>(src, dst, cursor, elist);

    // aggregate + fused GEMM
    if (bigws) {
        agg_a<<<(NN + 3) / 4, 256, 0, stream>>>(h1b, rowptr, elist, out);
        gemm_a<<<(NN + 63) / 64, 256, 0, stream>>>(x, h1b, wb, bl, out);
    } else {
        agg_b<<<NN / 2, 256, 0, stream>>>(x, batch, A1, B1, rowptr, elist, out);
        gemm_b<<<(NN + BM - 1) / BM, 256, 0, stream>>>(x, batch, A1, B1, wl, bl, wr, out);
    }

    // norm2 stats + apply
    stats_p1<<<NBROW, 256, 0, stream>>>(out, batch, A2, B2);
    finalize_kernel<<<GG + 2, 128, 0, stream>>>(batch, A2, B2, n2w, n2b, n2ms,
                                                (unsigned short*)nullptr,
                                                (const float*)nullptr, (const float*)nullptr, 0);
    apply_kernel<<<(NN * 32 + 255) / 256, 256, 0, stream>>>(out, batch, A2, B2);
}

// Round 7
// 309.175 us; speedup vs baseline: 1.0838x; 1.0838x over previous
//
#include <hip/hip_runtime.h>
#include <math.h>

#define NN 100000
#define EE 600000
#define DD 128
#define GG 256
#define EPSV 1e-5f

typedef __attribute__((ext_vector_type(8))) __bf16 bf16x8;
typedef __attribute__((ext_vector_type(16))) float f32x16;
typedef __attribute__((ext_vector_type(4))) unsigned short us4;

// ---------------- workspace layout (bytes) ----------------
// A1/B1 double as Sg1/Qg1 (finalize converts in place); A2/B2 as Sg2/Qg2.
#define OFF_A1      0
#define OFF_B1      131072
#define OFF_A2      262144
#define OFF_B2      393216
#define OFF_DEG     524288      // N ints -> ends 924,288 (one memset covers A/B/deg)
#define OFF_ROWPTR  924288      // N+1 ints
#define OFF_CURSOR  1324352     // N ints
#define OFF_BSUMS   1724352     // <=512 ints
#define OFF_ELIST   1728448     // E ints  -> ends 4,128,448
#define OFF_WB      4128448     // 128*256 bf16 = 65,536 -> ends 4,193,984
#define OFF_H1B     4193984     // N*128 bf16 = 25,600,000
#define WS_NEED_A   (OFF_H1B + 25600000ULL)

#define NB_STATS 782            // (NN+127)/128
#define NB_EDGE  2344           // (EE+255)/256
#define NB_H1B   12500          // NN*32/256
#define NB1024   98             // (NN+1023)/1024

__device__ __forceinline__ int lower_bound_i(const int* __restrict__ a, int n, int v) {
    int lo = 0, hi = n;
    while (lo < hi) { int mid = (lo + hi) >> 1; if (a[mid] < v) lo = mid + 1; else hi = mid; }
    return lo;
}

__device__ __forceinline__ unsigned short f2bf(float f) {
    unsigned int u = __float_as_uint(f);
    unsigned int r = u + 0x7fffu + ((u >> 16) & 1u);
    return (unsigned short)(r >> 16);
}

// ---------------- stats phase-1 body: 128 rows/block partial sums -> atomics ----------------
__device__ __forceinline__ void stats_body(
    const float* __restrict__ X, const int* __restrict__ batch,
    float* __restrict__ Sg, float* __restrict__ Qg, int blk)
{
    int t = threadIdx.x;
    int rl = t >> 5, fq = t & 31;
    int r0 = blk * 128;
    int rend = r0 + 128; if (rend > NN) rend = NN;
    __shared__ float ls[8 * 128];
    __shared__ float lq[8 * 128];
    int g0 = batch[r0], g1 = batch[rend - 1];
    const float4* X4 = (const float4*)X;
    for (int g = g0; g <= g1; ++g) {
        int sa = (g == g0) ? r0   : lower_bound_i(batch, NN, g);
        int sb = (g == g1) ? rend : lower_bound_i(batch, NN, g + 1);
        float s0 = 0.f, s1 = 0.f, s2 = 0.f, s3 = 0.f;
        float q0 = 0.f, q1 = 0.f, q2 = 0.f, q3 = 0.f;
        for (int r = sa + rl; r < sb; r += 8) {
            float4 v = X4[r * 32 + fq];
            s0 += v.x; s1 += v.y; s2 += v.z; s3 += v.w;
            q0 += v.x * v.x; q1 += v.y * v.y; q2 += v.z * v.z; q3 += v.w * v.w;
        }
        ls[rl * 128 + fq * 4 + 0] = s0; ls[rl * 128 + fq * 4 + 1] = s1;
        ls[rl * 128 + fq * 4 + 2] = s2; ls[rl * 128 + fq * 4 + 3] = s3;
        lq[rl * 128 + fq * 4 + 0] = q0; lq[rl * 128 + fq * 4 + 1] = q1;
        lq[rl * 128 + fq * 4 + 2] = q2; lq[rl * 128 + fq * 4 + 3] = q3;
        __syncthreads();
        if (t < 32) {
            #pragma unroll
            for (int k = 0; k < 4; k++) {
                float as = 0.f, aq = 0.f;
                #pragma unroll
                for (int j = 0; j < 8; j++) { as += ls[j * 128 + t * 4 + k]; aq += lq[j * 128 + t * 4 + k]; }
                atomicAdd(&Sg[g * DD + t * 4 + k], as);
                atomicAdd(&Qg[g * DD + t * 4 + k], aq);
            }
        }
        __syncthreads();
    }
}

// stats_p1 standalone (used for path B's second norm)
__global__ __launch_bounds__(256) void stats_p1(
    const float* __restrict__ X, const int* __restrict__ batch,
    float* __restrict__ Sg, float* __restrict__ Qg)
{
    stats_body(X, batch, Sg, Qg, blockIdx.x);
}

// stats_p1 on X  +  deg count, fused by block range
__global__ __launch_bounds__(256) void statsdeg_kernel(
    const float* __restrict__ X, const int* __restrict__ batch,
    float* __restrict__ Sg, float* __restrict__ Qg,
    const int* __restrict__ dst, int* __restrict__ deg)
{
    int b = blockIdx.x;
    if (b < NB_STATS) { stats_body(X, batch, Sg, Qg, b); return; }
    int e = (b - NB_STATS) * 256 + threadIdx.x;
    if (e < EE) atomicAdd(&deg[dst[e]], 1);
}

// ---------------- finalize: Sg/Qg -> A/B in place; blocks GG/GG+1 convert weights ----------------
__global__ __launch_bounds__(128) void finalize_kernel(
    const int* __restrict__ batch, float* S, float* Q,
    const float* __restrict__ w, const float* __restrict__ bb, const float* __restrict__ ms,
    unsigned short* __restrict__ wb, const float* __restrict__ wl, const float* __restrict__ wr,
    int doW)
{
    int g = blockIdx.x;
    if (g >= GG) {
        if (!doW) return;
        const float* W = (g == GG) ? wl : wr;
        int kofs = (g == GG) ? 0 : 128;
        for (int tt = threadIdx.x; tt < DD * 32; tt += 128) {
            int j = tt >> 5, k4 = tt & 31;
            float4 v = ((const float4*)W)[j * 32 + k4];
            us4 o = { f2bf(v.x), f2bf(v.y), f2bf(v.z), f2bf(v.w) };
            *(us4*)&wb[j * 256 + kofs + k4 * 4] = o;
        }
        return;
    }
    __shared__ int sh[2];
    if (threadIdx.x == 0) { sh[0] = lower_bound_i(batch, NN, g); sh[1] = lower_bound_i(batch, NN, g + 1); }
    __syncthreads();
    int cnt = sh[1] - sh[0];
    float c = (float)(cnt > 0 ? cnt : 1);
    float inv_c = 1.0f / c;
    int d = threadIdx.x;
    float m  = S[g * DD + d] * inv_c;
    float qm = Q[g * DD + d] * inv_c;
    float sc = ms[d];
    float var = qm - m * m * sc * (2.0f - sc);
    float Ad = w[d] * rsqrtf(var + EPSV);
    S[g * DD + d] = Ad;
    Q[g * DD + d] = bb[d] - Ad * m * sc;
}

// ---------------- h1b = bf16(A1*x + B1) + scan1, fused by block range ----------------
__global__ __launch_bounds__(256) void h1bscan_kernel(
    const float* __restrict__ X, const int* __restrict__ batch,
    const float* __restrict__ A1, const float* __restrict__ B1, unsigned short* __restrict__ h1b,
    const int* __restrict__ deg, int* __restrict__ bsums)
{
    int blk = blockIdx.x;
    if (blk < NB_H1B) {
        int f = blk * 256 + threadIdx.x;
        int i = f >> 5, c = f & 31;
        int g = batch[i];
        float4 v = ((const float4*)X)[f];
        float4 a = ((const float4*)A1)[g * 32 + c];
        float4 b = ((const float4*)B1)[g * 32 + c];
        us4 o = { f2bf(fmaf(a.x, v.x, b.x)), f2bf(fmaf(a.y, v.y, b.y)),
                  f2bf(fmaf(a.z, v.z, b.z)), f2bf(fmaf(a.w, v.w, b.w)) };
        *(us4*)&h1b[i * DD + c * 4] = o;
        return;
    }
    // scan1 part
    int b = blk - NB_H1B, t = threadIdx.x;
    int base = b * 1024 + t * 4;
    int v = 0;
    #pragma unroll
    for (int k = 0; k < 4; k++) { int i = base + k; if (i < NN) v += deg[i]; }
    __shared__ int sd[256];
    sd[t] = v; __syncthreads();
    for (int off = 128; off > 0; off >>= 1) { if (t < off) sd[t] += sd[t + off]; __syncthreads(); }
    if (t == 0) bsums[b] = sd[0];
}

// scan1 standalone (path B)
__global__ __launch_bounds__(256) void scan1(const int* __restrict__ deg, int* __restrict__ bsums) {
    int b = blockIdx.x, t = threadIdx.x;
    int base = b * 1024 + t * 4;
    int v = 0;
    #pragma unroll
    for (int k = 0; k < 4; k++) { int i = base + k; if (i < NN) v += deg[i]; }
    __shared__ int sd[256];
    sd[t] = v; __syncthreads();
    for (int off = 128; off > 0; off >>= 1) { if (t < off) sd[t] += sd[t + off]; __syncthreads(); }
    if (t == 0) bsums[b] = sd[0];
}

__global__ __launch_bounds__(256) void scan3(const int* __restrict__ deg, const int* __restrict__ bsums,
                                             int* __restrict__ rowptr, int* __restrict__ cursor) {
    int b = blockIdx.x, t = threadIdx.x;
    int boff = 0;
    for (int j = 0; j < b; j++) boff += bsums[j];
    int base = b * 1024 + t * 4;
    int d0 = 0, d1 = 0, d2 = 0, d3 = 0;
    if (base     < NN) d0 = deg[base];
    if (base + 1 < NN) d1 = deg[base + 1];
    if (base + 2 < NN) d2 = deg[base + 2];
    if (base + 3 < NN) d3 = deg[base + 3];
    int tsum = d0 + d1 + d2 + d3;
    __shared__ int sd[256];
    sd[t] = tsum; __syncthreads();
    for (int off = 1; off < 256; off <<= 1) {
        int a = (t >= off) ? sd[t - off] : 0;
        __syncthreads();
        sd[t] += a;
        __syncthreads();
    }
    int exc = sd[t] - tsum + boff;
    int p0 = exc, p1 = exc + d0, p2 = exc + d0 + d1, p3 = exc + d0 + d1 + d2;
    if (base     < NN) { rowptr[base]     = p0; cursor[base]     = p0; }
    if (base + 1 < NN) { rowptr[base + 1] = p1; cursor[base + 1] = p1; }
    if (base + 2 < NN) { rowptr[base + 2] = p2; cursor[base + 2] = p2; }
    if (base + 3 < NN) { rowptr[base + 3] = p3; cursor[base + 3] = p3; }
    if (b == 0 && t == 0) rowptr[NN] = EE;
}

__global__ __launch_bounds__(256) void fill_kernel(const int* __restrict__ src, const int* __restrict__ dst,
                                                   int* __restrict__ cursor, int* __restrict__ elist) {
    int e = blockIdx.x * 256 + threadIdx.x;
    if (e < EE) {
        int p = atomicAdd(&cursor[dst[e]], 1);
        elist[p] = src[e];
    }
}

// ---------------- mega kernel: gather-max + GEMM + residual/ReLU + norm2 partial sums ----------------
// 64 rows x 128 cols per block, 512 threads (8 waves). A-tile (agg|h1) built in LDS.
#define USTR 264
__global__ __launch_bounds__(512) void gemm_mega(
    const float* __restrict__ X, const unsigned short* __restrict__ h1b,
    const int* __restrict__ batch, const int* __restrict__ rowptr, const int* __restrict__ elist,
    const unsigned short* __restrict__ wb, const float* __restrict__ blv,
    float* __restrict__ Sg2, float* __restrict__ Qg2, float* __restrict__ out)
{
    __shared__ unsigned short sU[64 * USTR];   // 33.8 KB
    __shared__ int sBatch[64];
    int tid = threadIdx.x;
    int i0 = blockIdx.x * 64;
    int lane = tid & 63, wave = tid >> 6;
    int m = lane & 31, hf = lane >> 5;

    // stage h1 half of A-tile (k 128..255)
    for (int t = tid; t < 64 * 16; t += 512) {
        int r = t >> 4, c = t & 15;
        int i = i0 + r; if (i >= NN) i = NN - 1;
        uint4 v = ((const uint4*)(h1b + (size_t)i * DD))[c];
        *(uint4*)&sU[r * USTR + 128 + c * 8] = v;
    }
    if (tid < 64) {
        int i = i0 + tid;
        sBatch[tid] = (i < NN) ? batch[i] : -1;
    }

    // gather agg half of A-tile (k 0..127): wave handles rows wave, wave+8, ...
    for (int rr = wave; rr < 64; rr += 8) {
        int i = i0 + rr;
        int beg = 0, end = 0;
        if (i < NN) { beg = rowptr[i]; end = rowptr[i + 1]; }
        float a0 = -INFINITY, a1 = -INFINITY, a2 = -INFINITY, a3 = -INFINITY;
        int last = end - 1;
        for (int e = beg; e < end; e += 8) {
            int e0 = e + hf;
            int n0 = elist[e0     < last ? e0     : last];
            int n1 = elist[e0 + 2 < last ? e0 + 2 : last];
            int n2 = elist[e0 + 4 < last ? e0 + 4 : last];
            int n3 = elist[e0 + 6 < last ? e0 + 6 : last];
            us4 p0 = *(const us4*)(h1b + n0 * DD + m * 4);
            us4 p1 = *(const us4*)(h1b + n1 * DD + m * 4);
            us4 p2 = *(const us4*)(h1b + n2 * DD + m * 4);
            us4 p3 = *(const us4*)(h1b + n3 * DD + m * 4);
            a0 = fmaxf(a0, fmaxf(fmaxf(__uint_as_float((unsigned)p0[0] << 16), __uint_as_float((unsigned)p1[0] << 16)),
                                 fmaxf(__uint_as_float((unsigned)p2[0] << 16), __uint_as_float((unsigned)p3[0] << 16))));
            a1 = fmaxf(a1, fmaxf(fmaxf(__uint_as_float((unsigned)p0[1] << 16), __uint_as_float((unsigned)p1[1] << 16)),
                                 fmaxf(__uint_as_float((unsigned)p2[1] << 16), __uint_as_float((unsigned)p3[1] << 16))));
            a2 = fmaxf(a2, fmaxf(fmaxf(__uint_as_float((unsigned)p0[2] << 16), __uint_as_float((unsigned)p1[2] << 16)),
                                 fmaxf(__uint_as_float((unsigned)p2[2] << 16), __uint_as_float((unsigned)p3[2] << 16))));
            a3 = fmaxf(a3, fmaxf(fmaxf(__uint_as_float((unsigned)p0[3] << 16), __uint_as_float((unsigned)p1[3] << 16)),
                                 fmaxf(__uint_as_float((unsigned)p2[3] << 16), __uint_as_float((unsigned)p3[3] << 16))));
        }
        a0 = fmaxf(a0, __shfl_xor(a0, 32, 64));
        a1 = fmaxf(a1, __shfl_xor(a1, 32, 64));
        a2 = fmaxf(a2, __shfl_xor(a2, 32, 64));
        a3 = fmaxf(a3, __shfl_xor(a3, 32, 64));
        if (hf == 0) {
            us4 r4 = { 0, 0, 0, 0 };
            if (end > beg) {
                r4[0] = (unsigned short)(__float_as_uint(a0) >> 16);
                r4[1] = (unsigned short)(__float_as_uint(a1) >> 16);
                r4[2] = (unsigned short)(__float_as_uint(a2) >> 16);
                r4[3] = (unsigned short)(__float_as_uint(a3) >> 16);
            }
            *(us4*)&sU[rr * USTR + m * 4] = r4;
        }
    }
    __syncthreads();

    // MFMA: wave -> rows rbase..rbase+31, cols colgrp*32..+31
    int rbase = (wave >> 2) * 32;
    int col = (wave & 3) * 32 + m;
    const unsigned short* bcol = wb + col * 256 + hf * 8;
    const unsigned short* arow = &sU[(rbase + m) * USTR + hf * 8];

    f32x16 acc;
    #pragma unroll
    for (int r = 0; r < 16; r++) acc[r] = 0.f;
    #pragma unroll
    for (int s = 0; s < 16; s++) {
        bf16x8 b = *(const bf16x8*)(bcol + s * 16);
        bf16x8 a = *(const bf16x8*)(arow + s * 16);
        acc = __builtin_amdgcn_mfma_f32_32x32x16_bf16(a, b, acc, 0, 0, 0);
    }

    // epilogue: h2 = relu(x + bl + acc), write + per-graph run-length stats atomics
    float blc = blv[col];
    float s_run = 0.f, q_run = 0.f;
    int cur_g = -1;
    #pragma unroll
    for (int reg = 0; reg < 16; reg++) {
        int rl = (reg & 3) + 8 * (reg >> 2) + 4 * hf;
        int i = i0 + rbase + rl;
        if (i < NN) {
            float v = X[i * DD + col] + blc + acc[reg];
            v = v > 0.f ? v : 0.f;
            out[i * DD + col] = v;
            int g = sBatch[rbase + rl];
            if (g != cur_g) {
                if (cur_g >= 0) {
                    atomicAdd(&Sg2[cur_g * DD + col], s_run);
                    atomicAdd(&Qg2[cur_g * DD + col], q_run);
                }
                cur_g = g; s_run = 0.f; q_run = 0.f;
            }
            s_run += v; q_run += v * v;
        }
    }
    if (cur_g >= 0) {
        atomicAdd(&Sg2[cur_g * DD + col], s_run);
        atomicAdd(&Qg2[cur_g * DD + col], q_run);
    }
}

// ---------------- norm2 apply in place on d_out ----------------
__global__ __launch_bounds__(256) void apply_kernel(float* __restrict__ H, const int* __restrict__ batch,
                                                    const float* __restrict__ A2, const float* __restrict__ B2) {
    int f = blockIdx.x * 256 + threadIdx.x;
    if (f >= NN * 32) return;
    int i = f >> 5, c = f & 31;
    int g = batch[i];
    float4 v = ((float4*)H)[f];
    float4 a = ((const float4*)A2)[g * 32 + c];
    float4 b = ((const float4*)B2)[g * 32 + c];
    v.x = fmaf(a.x, v.x, b.x); v.y = fmaf(a.y, v.y, b.y);
    v.z = fmaf(a.z, v.z, b.z); v.w = fmaf(a.w, v.w, b.w);
    ((float4*)H)[f] = v;
}

// ---------------- fallback path B: fp32 agg + LDS gemm ----------------
__global__ __launch_bounds__(256) void agg_b(
    const float* __restrict__ X, const int* __restrict__ batch,
    const float* __restrict__ A1, const float* __restrict__ B1,
    const int* __restrict__ rowptr, const int* __restrict__ elist, float* __restrict__ H)
{
    int i = blockIdx.x * 2 + (threadIdx.x >> 7);
    int d = threadIdx.x & 127;
    int beg = rowptr[i], end = rowptr[i + 1];
    float acc = -INFINITY;
    int e = beg;
    for (; e + 2 <= end; e += 2) {
        int s0 = elist[e], s1 = elist[e + 1];
        int g0 = batch[s0], g1 = batch[s1];
        float v0 = fmaf(A1[g0 * DD + d], X[s0 * DD + d], B1[g0 * DD + d]);
        float v1 = fmaf(A1[g1 * DD + d], X[s1 * DD + d], B1[g1 * DD + d]);
        acc = fmaxf(acc, fmaxf(v0, v1));
    }
    for (; e < end; e++) {
        int s = elist[e]; int g = batch[s];
        acc = fmaxf(acc, fmaf(A1[g * DD + d], X[s * DD + d], B1[g * DD + d]));
    }
    if (end == beg) acc = 0.f;
    H[i * DD + d] = acc;
}

#define BM 128
#define LDT 72
__global__ __launch_bounds__(256) void gemm_b(
    const float* __restrict__ X, const int* __restrict__ batch,
    const float* __restrict__ A1, const float* __restrict__ B1,
    const float* __restrict__ wl, const float* __restrict__ blv, const float* __restrict__ wr,
    float* __restrict__ H)
{
    __shared__ unsigned short Ut[BM * LDT];
    __shared__ unsigned short Wt[DD * LDT];
    int i0 = blockIdx.x * BM;
    int tid = threadIdx.x;
    int lane = tid & 63, wave = tid >> 6;
    int wrow = (wave >> 1) * 64, wcol = (wave & 1) * 64;
    int m = lane & 31, hf = lane >> 5;

    f32x16 acc00, acc01, acc10, acc11;
    #pragma unroll
    for (int r = 0; r < 16; r++) { acc00[r] = 0.f; acc01[r] = 0.f; acc10[r] = 0.f; acc11[r] = 0.f; }

    for (int c = 0; c < 4; c++) {
        __syncthreads();
        for (int t = tid; t < BM * 16; t += 256) {
            int r = t >> 4, c4 = t & 15;
            int i = i0 + r; if (i >= NN) i = NN - 1;
            float4 v;
            if (c < 2) {
                v = ((const float4*)H)[i * 32 + c * 16 + c4];
            } else {
                int g = batch[i];
                float4 xv = ((const float4*)X)[i * 32 + (c - 2) * 16 + c4];
                float4 a = ((const float4*)A1)[g * 32 + (c - 2) * 16 + c4];
                float4 b = ((const float4*)B1)[g * 32 + (c - 2) * 16 + c4];
                v.x = fmaf(a.x, xv.x, b.x); v.y = fmaf(a.y, xv.y, b.y);
                v.z = fmaf(a.z, xv.z, b.z); v.w = fmaf(a.w, xv.w, b.w);
            }
            us4 o = { f2bf(v.x), f2bf(v.y), f2bf(v.z), f2bf(v.w) };
            *(us4*)&Ut[r * LDT + c4 * 4] = o;
        }
        {
            const float* Wsrc = (c < 2) ? wl : wr;
            int kb = (c & 1) * 16;
            for (int t = tid; t < DD * 16; t += 256) {
                int j = t >> 4, c4 = t & 15;
                float4 v = ((const float4*)Wsrc)[j * 32 + kb + c4];
                us4 o = { f2bf(v.x), f2bf(v.y), f2bf(v.z), f2bf(v.w) };
                *(us4*)&Wt[j * LDT + c4 * 4] = o;
            }
        }
        __syncthreads();
        #pragma unroll
        for (int kk = 0; kk < 4; kk++) {
            int kb2 = kk * 16 + hf * 8;
            bf16x8 a0 = *(const bf16x8*)&Ut[(wrow      + m) * LDT + kb2];
            bf16x8 a1 = *(const bf16x8*)&Ut[(wrow + 32 + m) * LDT + kb2];
            bf16x8 b0 = *(const bf16x8*)&Wt[(wcol      + m) * LDT + kb2];
            bf16x8 b1 = *(const bf16x8*)&Wt[(wcol + 32 + m) * LDT + kb2];
            acc00 = __builtin_amdgcn_mfma_f32_32x32x16_bf16(a0, b0, acc00, 0, 0, 0);
            acc01 = __builtin_amdgcn_mfma_f32_32x32x16_bf16(a0, b1, acc01, 0, 0, 0);
            acc10 = __builtin_amdgcn_mfma_f32_32x32x16_bf16(a1, b0, acc10, 0, 0, 0);
            acc11 = __builtin_amdgcn_mfma_f32_32x32x16_bf16(a1, b1, acc11, 0, 0, 0);
        }
    }

    int col0 = wcol + m, col1 = wcol + 32 + m;
    float bl0 = blv[col0], bl1 = blv[col1];
    #pragma unroll
    for (int reg = 0; reg < 16; reg++) {
        int rl = (reg & 3) + 8 * (reg >> 2) + 4 * hf;
        int ia = i0 + wrow + rl;
        int ib = i0 + wrow + 32 + rl;
        if (ia < NN) {
            float v0 = X[ia * DD + col0] + bl0 + acc00[reg];
            float v1 = X[ia * DD + col1] + bl1 + acc01[reg];
            H[ia * DD + col0] = v0 > 0.f ? v0 : 0.f;
            H[ia * DD + col1] = v1 > 0.f ? v1 : 0.f;
        }
        if (ib < NN) {
            float v0 = X[ib * DD + col0] + bl0 + acc10[reg];
            float v1 = X[ib * DD + col1] + bl1 + acc11[reg];
            H[ib * DD + col0] = v0 > 0.f ? v0 : 0.f;
            H[ib * DD + col1] = v1 > 0.f ? v1 : 0.f;
        }
    }
}

extern "C" void kernel_launch(void* const* d_in, const int* in_sizes, int n_in,
                              void* d_out, int out_size, void* d_ws, size_t ws_size,
                              hipStream_t stream) {
    const float* x    = (const float*)d_in[0];
    const int*   ei   = (const int*)d_in[1];
    const int*   batch= (const int*)d_in[2];
    const float* n1w  = (const float*)d_in[3];
    const float* n1b  = (const float*)d_in[4];
    const float* n1ms = (const float*)d_in[5];
    const float* n2w  = (const float*)d_in[6];
    const float* n2b  = (const float*)d_in[7];
    const float* n2ms = (const float*)d_in[8];
    const float* wl   = (const float*)d_in[9];
    const float* bl   = (const float*)d_in[10];
    const float* wr   = (const float*)d_in[11];
    float* out = (float*)d_out;

    char* w = (char*)d_ws;
    float* A1     = (float*)(w + OFF_A1);     // Sg1 -> A1
    float* B1     = (float*)(w + OFF_B1);     // Qg1 -> B1
    float* A2     = (float*)(w + OFF_A2);     // Sg2 -> A2
    float* B2     = (float*)(w + OFF_B2);     // Qg2 -> B2
    int*   deg    = (int*)(w + OFF_DEG);
    int*   rowptr = (int*)(w + OFF_ROWPTR);
    int*   cursor = (int*)(w + OFF_CURSOR);
    int*   bsums  = (int*)(w + OFF_BSUMS);
    int*   elist  = (int*)(w + OFF_ELIST);
    unsigned short* wb  = (unsigned short*)(w + OFF_WB);
    unsigned short* h1b = (unsigned short*)(w + OFF_H1B);

    const int* src = ei;
    const int* dst = ei + EE;
    bool bigws = (ws_size >= WS_NEED_A);

    // zero Sg1/Qg1/Sg2/Qg2 and deg in one contiguous memset
    hipMemsetAsync(w, 0, OFF_ROWPTR, stream);

    // norm1 stats + deg (fused)
    statsdeg_kernel<<<NB_STATS + NB_EDGE, 256, 0, stream>>>(x, batch, A1, B1, dst, deg);
    finalize_kernel<<<GG + 2, 128, 0, stream>>>(batch, A1, B1, n1w, n1b, n1ms,
                                                wb, wl, wr, bigws ? 1 : 0);

    if (bigws) {
        // h1b conversion + scan1 (fused)
        h1bscan_kernel<<<NB_H1B + NB1024, 256, 0, stream>>>(x, batch, A1, B1, h1b, deg, bsums);
        scan3<<<NB1024, 256, 0, stream>>>(deg, bsums, rowptr, cursor);
        fill_kernel<<<NB_EDGE, 256, 0, stream>>>(src, dst, cursor, elist);

        // gather-max + GEMM + residual/relu + norm2 partial sums (fused)
        gemm_mega<<<(NN + 63) / 64, 512, 0, stream>>>(x, h1b, batch, rowptr, elist,
                                                      wb, bl, A2, B2, out);

        finalize_kernel<<<GG, 128, 0, stream>>>(batch, A2, B2, n2w, n2b, n2ms,
                                                (unsigned short*)nullptr,
                                                (const float*)nullptr, (const float*)nullptr, 0);
        apply_kernel<<<NB_H1B, 256, 0, stream>>>(out, batch, A2, B2);
    } else {
        scan1<<<NB1024, 256, 0, stream>>>(deg, bsums);
        scan3<<<NB1024, 256, 0, stream>>>(deg, bsums, rowptr, cursor);
        fill_kernel<<<NB_EDGE, 256, 0, stream>>>(src, dst, cursor, elist);

        agg_b<<<NN / 2, 256, 0, stream>>>(x, batch, A1, B1, rowptr, elist, out);
        gemm_b<<<(NN + BM - 1) / BM, 256, 0, stream>>>(x, batch, A1, B1, wl, bl, wr, out);

        stats_p1<<<NB_STATS, 256, 0, stream>>>(out, batch, A2, B2);
        finalize_kernel<<<GG, 128, 0, stream>>>(batch, A2, B2, n2w, n2b, n2ms,
                                                (unsigned short*)nullptr,
                                                (const float*)nullptr, (const float*)nullptr, 0);
        apply_kernel<<<NB_H1B, 256, 0, stream>>>(out, batch, A2, B2);
    }
}

// Round 8
// 299.627 us; speedup vs baseline: 1.1184x; 1.0319x over previous
//
#include <hip/hip_runtime.h>
#include <math.h>

#define NN 100000
#define EE 600000
#define DD 128
#define GG 256
#define EPSV 1e-5f

typedef __attribute__((ext_vector_type(8))) __bf16 bf16x8;
typedef __attribute__((ext_vector_type(16))) float f32x16;
typedef __attribute__((ext_vector_type(4))) unsigned short us4;

// ---------------- workspace layout (bytes) ----------------
// A1/B1 double as Sg1/Qg1 (finalize converts in place); A2/B2 as Sg2/Qg2.
#define OFF_A1      0
#define OFF_B1      131072
#define OFF_A2      262144
#define OFF_B2      393216
#define OFF_DEG     524288      // N ints -> ends 924,288 (one memset covers A/B/deg)
#define OFF_ROWPTR  924288      // N+1 ints
#define OFF_CURSOR  1324352     // N ints
#define OFF_BSUMS   1724352     // <=512 ints
#define OFF_CNT     1726400     // G ints (per-graph node counts)
#define OFF_ELIST   1728448     // E ints  -> ends 4,128,448
#define OFF_WB      4128448     // 128*256 bf16 = 65,536 -> ends 4,193,984
#define OFF_H1B     4193984     // N*128 bf16 = 25,600,000
#define WS_NEED_A   (OFF_H1B + 25600000ULL)

#define NB_STATS 782            // (NN+127)/128
#define NB_EDGE  2344           // (EE+255)/256
#define NB_H1B   12500          // NN*32/256
#define NB1024   98             // (NN+1023)/1024

__device__ __forceinline__ int lower_bound_i(const int* __restrict__ a, int n, int v) {
    int lo = 0, hi = n;
    while (lo < hi) { int mid = (lo + hi) >> 1; if (a[mid] < v) lo = mid + 1; else hi = mid; }
    return lo;
}

__device__ __forceinline__ unsigned short f2bf(float f) {
    unsigned int u = __float_as_uint(f);
    unsigned int r = u + 0x7fffu + ((u >> 16) & 1u);
    return (unsigned short)(r >> 16);
}

// ---------------- stats phase-1 body: 128 rows/block partial sums -> atomics ----------------
__device__ __forceinline__ void stats_body(
    const float* __restrict__ X, const int* __restrict__ batch,
    float* __restrict__ Sg, float* __restrict__ Qg, int blk)
{
    int t = threadIdx.x;
    int rl = t >> 5, fq = t & 31;
    int r0 = blk * 128;
    int rend = r0 + 128; if (rend > NN) rend = NN;
    __shared__ float ls[8 * 128];
    __shared__ float lq[8 * 128];
    int g0 = batch[r0], g1 = batch[rend - 1];
    const float4* X4 = (const float4*)X;
    for (int g = g0; g <= g1; ++g) {
        int sa = (g == g0) ? r0   : lower_bound_i(batch, NN, g);
        int sb = (g == g1) ? rend : lower_bound_i(batch, NN, g + 1);
        float s0 = 0.f, s1 = 0.f, s2 = 0.f, s3 = 0.f;
        float q0 = 0.f, q1 = 0.f, q2 = 0.f, q3 = 0.f;
        for (int r = sa + rl; r < sb; r += 8) {
            float4 v = X4[r * 32 + fq];
            s0 += v.x; s1 += v.y; s2 += v.z; s3 += v.w;
            q0 += v.x * v.x; q1 += v.y * v.y; q2 += v.z * v.z; q3 += v.w * v.w;
        }
        ls[rl * 128 + fq * 4 + 0] = s0; ls[rl * 128 + fq * 4 + 1] = s1;
        ls[rl * 128 + fq * 4 + 2] = s2; ls[rl * 128 + fq * 4 + 3] = s3;
        lq[rl * 128 + fq * 4 + 0] = q0; lq[rl * 128 + fq * 4 + 1] = q1;
        lq[rl * 128 + fq * 4 + 2] = q2; lq[rl * 128 + fq * 4 + 3] = q3;
        __syncthreads();
        if (t < 32) {
            #pragma unroll
            for (int k = 0; k < 4; k++) {
                float as = 0.f, aq = 0.f;
                #pragma unroll
                for (int j = 0; j < 8; j++) { as += ls[j * 128 + t * 4 + k]; aq += lq[j * 128 + t * 4 + k]; }
                atomicAdd(&Sg[g * DD + t * 4 + k], as);
                atomicAdd(&Qg[g * DD + t * 4 + k], aq);
            }
        }
        __syncthreads();
    }
}

// stats_p1 standalone (path B second norm)
__global__ __launch_bounds__(256) void stats_p1(
    const float* __restrict__ X, const int* __restrict__ batch,
    float* __restrict__ Sg, float* __restrict__ Qg)
{
    stats_body(X, batch, Sg, Qg, blockIdx.x);
}

// stats_p1 on X  +  deg count, fused by block range
__global__ __launch_bounds__(256) void statsdeg_kernel(
    const float* __restrict__ X, const int* __restrict__ batch,
    float* __restrict__ Sg, float* __restrict__ Qg,
    const int* __restrict__ dst, int* __restrict__ deg)
{
    int b = blockIdx.x;
    if (b < NB_STATS) { stats_body(X, batch, Sg, Qg, b); return; }
    int e = (b - NB_STATS) * 256 + threadIdx.x;
    if (e < EE) atomicAdd(&deg[dst[e]], 1);
}

// ---------------- finalize: Sg/Qg -> A/B in place (+cnt); blocks GG/GG+1 convert weights ----------------
__global__ __launch_bounds__(128) void finalize_kernel(
    const int* __restrict__ batch, float* S, float* Q,
    const float* __restrict__ w, const float* __restrict__ bb, const float* __restrict__ ms,
    unsigned short* __restrict__ wb, const float* __restrict__ wl, const float* __restrict__ wr,
    int* __restrict__ cnt, int doW)
{
    int g = blockIdx.x;
    if (g >= GG) {
        if (!doW) return;
        const float* W = (g == GG) ? wl : wr;
        int kofs = (g == GG) ? 0 : 128;
        for (int tt = threadIdx.x; tt < DD * 32; tt += 128) {
            int j = tt >> 5, k4 = tt & 31;
            float4 v = ((const float4*)W)[j * 32 + k4];
            us4 o = { f2bf(v.x), f2bf(v.y), f2bf(v.z), f2bf(v.w) };
            *(us4*)&wb[j * 256 + kofs + k4 * 4] = o;
        }
        return;
    }
    __shared__ int sh[2];
    if (threadIdx.x == 0) { sh[0] = lower_bound_i(batch, NN, g); sh[1] = lower_bound_i(batch, NN, g + 1); }
    __syncthreads();
    int c_n = sh[1] - sh[0];
    if (cnt && threadIdx.x == 0) cnt[g] = c_n;
    float c = (float)(c_n > 0 ? c_n : 1);
    float inv_c = 1.0f / c;
    int d = threadIdx.x;
    float m  = S[g * DD + d] * inv_c;
    float qm = Q[g * DD + d] * inv_c;
    float sc = ms[d];
    float var = qm - m * m * sc * (2.0f - sc);
    float Ad = w[d] * rsqrtf(var + EPSV);
    S[g * DD + d] = Ad;
    Q[g * DD + d] = bb[d] - Ad * m * sc;
}

// ---------------- h1b = bf16(A1*x + B1) + scan1, fused by block range ----------------
__global__ __launch_bounds__(256) void h1bscan_kernel(
    const float* __restrict__ X, const int* __restrict__ batch,
    const float* __restrict__ A1, const float* __restrict__ B1, unsigned short* __restrict__ h1b,
    const int* __restrict__ deg, int* __restrict__ bsums)
{
    int blk = blockIdx.x;
    if (blk < NB_H1B) {
        int f = blk * 256 + threadIdx.x;
        int i = f >> 5, c = f & 31;
        int g = batch[i];
        float4 v = ((const float4*)X)[f];
        float4 a = ((const float4*)A1)[g * 32 + c];
        float4 b = ((const float4*)B1)[g * 32 + c];
        us4 o = { f2bf(fmaf(a.x, v.x, b.x)), f2bf(fmaf(a.y, v.y, b.y)),
                  f2bf(fmaf(a.z, v.z, b.z)), f2bf(fmaf(a.w, v.w, b.w)) };
        *(us4*)&h1b[i * DD + c * 4] = o;
        return;
    }
    int b = blk - NB_H1B, t = threadIdx.x;
    int base = b * 1024 + t * 4;
    int v = 0;
    #pragma unroll
    for (int k = 0; k < 4; k++) { int i = base + k; if (i < NN) v += deg[i]; }
    __shared__ int sd[256];
    sd[t] = v; __syncthreads();
    for (int off = 128; off > 0; off >>= 1) { if (t < off) sd[t] += sd[t + off]; __syncthreads(); }
    if (t == 0) bsums[b] = sd[0];
}

// scan1 standalone (path B)
__global__ __launch_bounds__(256) void scan1(const int* __restrict__ deg, int* __restrict__ bsums) {
    int b = blockIdx.x, t = threadIdx.x;
    int base = b * 1024 + t * 4;
    int v = 0;
    #pragma unroll
    for (int k = 0; k < 4; k++) { int i = base + k; if (i < NN) v += deg[i]; }
    __shared__ int sd[256];
    sd[t] = v; __syncthreads();
    for (int off = 128; off > 0; off >>= 1) { if (t < off) sd[t] += sd[t + off]; __syncthreads(); }
    if (t == 0) bsums[b] = sd[0];
}

__global__ __launch_bounds__(256) void scan3(const int* __restrict__ deg, const int* __restrict__ bsums,
                                             int* __restrict__ rowptr, int* __restrict__ cursor) {
    int b = blockIdx.x, t = threadIdx.x;
    int boff = 0;
    for (int j = 0; j < b; j++) boff += bsums[j];
    int base = b * 1024 + t * 4;
    int d0 = 0, d1 = 0, d2 = 0, d3 = 0;
    if (base     < NN) d0 = deg[base];
    if (base + 1 < NN) d1 = deg[base + 1];
    if (base + 2 < NN) d2 = deg[base + 2];
    if (base + 3 < NN) d3 = deg[base + 3];
    int tsum = d0 + d1 + d2 + d3;
    __shared__ int sd[256];
    sd[t] = tsum; __syncthreads();
    for (int off = 1; off < 256; off <<= 1) {
        int a = (t >= off) ? sd[t - off] : 0;
        __syncthreads();
        sd[t] += a;
        __syncthreads();
    }
    int exc = sd[t] - tsum + boff;
    int p0 = exc, p1 = exc + d0, p2 = exc + d0 + d1, p3 = exc + d0 + d1 + d2;
    if (base     < NN) { rowptr[base]     = p0; cursor[base]     = p0; }
    if (base + 1 < NN) { rowptr[base + 1] = p1; cursor[base + 1] = p1; }
    if (base + 2 < NN) { rowptr[base + 2] = p2; cursor[base + 2] = p2; }
    if (base + 3 < NN) { rowptr[base + 3] = p3; cursor[base + 3] = p3; }
    if (b == 0 && t == 0) rowptr[NN] = EE;
}

__global__ __launch_bounds__(256) void fill_kernel(const int* __restrict__ src, const int* __restrict__ dst,
                                                   int* __restrict__ cursor, int* __restrict__ elist) {
    int e = blockIdx.x * 256 + threadIdx.x;
    if (e < EE) {
        int p = atomicAdd(&cursor[dst[e]], 1);
        elist[p] = src[e];
    }
}

// ---------------- mega kernel: gather-max + GEMM + residual/ReLU + norm2 partial sums ----------------
// 64 rows x 128 cols per block, 512 threads (8 waves / 16 half-waves).
// Gather: one HALF-WAVE per row (16 rows concurrent), 8 loads in flight per lane.
#define USTR 264
__global__ __launch_bounds__(512) void gemm_mega(
    const float* __restrict__ X, const unsigned short* __restrict__ h1b,
    const int* __restrict__ batch, const int* __restrict__ rowptr, const int* __restrict__ elist,
    const unsigned short* __restrict__ wb, const float* __restrict__ blv,
    float* __restrict__ Sg2, float* __restrict__ Qg2, float* __restrict__ out)
{
    __shared__ unsigned short sU[64 * USTR];   // 33.8 KB
    __shared__ int sBatch[64];
    int tid = threadIdx.x;
    int i0 = blockIdx.x * 64;
    int lane = tid & 63, wave = tid >> 6;
    int m = lane & 31, hf = lane >> 5;

    // stage h1 half of A-tile (k 128..255)
    for (int t = tid; t < 64 * 16; t += 512) {
        int r = t >> 4, c = t & 15;
        int i = i0 + r; if (i >= NN) i = NN - 1;
        uint4 v = ((const uint4*)(h1b + (size_t)i * DD))[c];
        *(uint4*)&sU[r * USTR + 128 + c * 8] = v;
    }
    if (tid < 64) {
        int i = i0 + tid;
        sBatch[tid] = (i < NN) ? batch[i] : -1;
    }

    // gather agg half of A-tile (k 0..127): half-wave hw owns rows hw, hw+16, hw+32, hw+48
    int hw = tid >> 5, j = tid & 31;
    for (int rr = hw; rr < 64; rr += 16) {
        int i = i0 + rr;
        int beg = 0, end = 0;
        if (i < NN) { beg = rowptr[i]; end = rowptr[i + 1]; }
        float a0 = -INFINITY, a1 = -INFINITY, a2 = -INFINITY, a3 = -INFINITY;
        int last = end - 1;
        for (int e = beg; e < end; e += 8) {
            int n[8];
            #pragma unroll
            for (int k = 0; k < 8; k++) { int t2 = e + k; n[k] = elist[t2 < last ? t2 : last]; }
            us4 p[8];
            #pragma unroll
            for (int k = 0; k < 8; k++) p[k] = *(const us4*)(h1b + (size_t)n[k] * DD + j * 4);
            #pragma unroll
            for (int k = 0; k < 8; k++) {
                a0 = fmaxf(a0, __uint_as_float((unsigned)p[k][0] << 16));
                a1 = fmaxf(a1, __uint_as_float((unsigned)p[k][1] << 16));
                a2 = fmaxf(a2, __uint_as_float((unsigned)p[k][2] << 16));
                a3 = fmaxf(a3, __uint_as_float((unsigned)p[k][3] << 16));
            }
        }
        us4 r4 = { 0, 0, 0, 0 };
        if (end > beg) {
            r4[0] = (unsigned short)(__float_as_uint(a0) >> 16);
            r4[1] = (unsigned short)(__float_as_uint(a1) >> 16);
            r4[2] = (unsigned short)(__float_as_uint(a2) >> 16);
            r4[3] = (unsigned short)(__float_as_uint(a3) >> 16);
        }
        *(us4*)&sU[rr * USTR + j * 4] = r4;
    }
    __syncthreads();

    // MFMA: wave -> rows rbase..rbase+31, cols colgrp*32..+31
    int rbase = (wave >> 2) * 32;
    int col = (wave & 3) * 32 + m;
    const unsigned short* bcol = wb + col * 256 + hf * 8;
    const unsigned short* arow = &sU[(rbase + m) * USTR + hf * 8];

    f32x16 acc;
    #pragma unroll
    for (int r = 0; r < 16; r++) acc[r] = 0.f;
    #pragma unroll
    for (int s = 0; s < 16; s++) {
        bf16x8 b = *(const bf16x8*)(bcol + s * 16);
        bf16x8 a = *(const bf16x8*)(arow + s * 16);
        acc = __builtin_amdgcn_mfma_f32_32x32x16_bf16(a, b, acc, 0, 0, 0);
    }

    // epilogue: h2 = relu(x + bl + acc), write + per-graph run-length stats atomics
    float blc = blv[col];
    float s_run = 0.f, q_run = 0.f;
    int cur_g = -1;
    #pragma unroll
    for (int reg = 0; reg < 16; reg++) {
        int rl = (reg & 3) + 8 * (reg >> 2) + 4 * hf;
        int i = i0 + rbase + rl;
        if (i < NN) {
            float v = X[i * DD + col] + blc + acc[reg];
            v = v > 0.f ? v : 0.f;
            out[i * DD + col] = v;
            int g = sBatch[rbase + rl];
            if (g != cur_g) {
                if (cur_g >= 0) {
                    atomicAdd(&Sg2[cur_g * DD + col], s_run);
                    atomicAdd(&Qg2[cur_g * DD + col], q_run);
                }
                cur_g = g; s_run = 0.f; q_run = 0.f;
            }
            s_run += v; q_run += v * v;
        }
    }
    if (cur_g >= 0) {
        atomicAdd(&Sg2[cur_g * DD + col], s_run);
        atomicAdd(&Qg2[cur_g * DD + col], q_run);
    }
}

// ---------------- fused apply (path A): finalize norm2 inline from Sg2/Qg2/cnt ----------------
__global__ __launch_bounds__(256) void apply_a(
    float* __restrict__ H, const int* __restrict__ batch,
    const float* __restrict__ Sg2, const float* __restrict__ Qg2, const int* __restrict__ cnt,
    const float* __restrict__ w2, const float* __restrict__ b2, const float* __restrict__ ms2)
{
    int f = blockIdx.x * 256 + threadIdx.x;
    if (f >= NN * 32) return;
    int i = f >> 5, c = f & 31;
    int g = batch[i];
    int cg = cnt[g];
    float invc = 1.0f / (float)(cg > 0 ? cg : 1);
    float4 S  = ((const float4*)Sg2)[g * 32 + c];
    float4 Q  = ((const float4*)Qg2)[g * 32 + c];
    float4 W  = ((const float4*)w2)[c];
    float4 Bv = ((const float4*)b2)[c];
    float4 Ms = ((const float4*)ms2)[c];
    float4 v = ((float4*)H)[f];
    {
        float mm = S.x * invc, qm = Q.x * invc;
        float A = W.x * rsqrtf(qm - mm * mm * Ms.x * (2.0f - Ms.x) + EPSV);
        v.x = fmaf(A, v.x, Bv.x - A * mm * Ms.x);
    }
    {
        float mm = S.y * invc, qm = Q.y * invc;
        float A = W.y * rsqrtf(qm - mm * mm * Ms.y * (2.0f - Ms.y) + EPSV);
        v.y = fmaf(A, v.y, Bv.y - A * mm * Ms.y);
    }
    {
        float mm = S.z * invc, qm = Q.z * invc;
        float A = W.z * rsqrtf(qm - mm * mm * Ms.z * (2.0f - Ms.z) + EPSV);
        v.z = fmaf(A, v.z, Bv.z - A * mm * Ms.z);
    }
    {
        float mm = S.w * invc, qm = Q.w * invc;
        float A = W.w * rsqrtf(qm - mm * mm * Ms.w * (2.0f - Ms.w) + EPSV);
        v.w = fmaf(A, v.w, Bv.w - A * mm * Ms.w);
    }
    ((float4*)H)[f] = v;
}

// ---------------- apply (path B): from precomputed A2/B2 ----------------
__global__ __launch_bounds__(256) void apply_b(float* __restrict__ H, const int* __restrict__ batch,
                                               const float* __restrict__ A2, const float* __restrict__ B2) {
    int f = blockIdx.x * 256 + threadIdx.x;
    if (f >= NN * 32) return;
    int i = f >> 5, c = f & 31;
    int g = batch[i];
    float4 v = ((float4*)H)[f];
    float4 a = ((const float4*)A2)[g * 32 + c];
    float4 b = ((const float4*)B2)[g * 32 + c];
    v.x = fmaf(a.x, v.x, b.x); v.y = fmaf(a.y, v.y, b.y);
    v.z = fmaf(a.z, v.z, b.z); v.w = fmaf(a.w, v.w, b.w);
    ((float4*)H)[f] = v;
}

// ---------------- fallback path B: fp32 agg + LDS gemm ----------------
__global__ __launch_bounds__(256) void agg_b(
    const float* __restrict__ X, const int* __restrict__ batch,
    const float* __restrict__ A1, const float* __restrict__ B1,
    const int* __restrict__ rowptr, const int* __restrict__ elist, float* __restrict__ H)
{
    int i = blockIdx.x * 2 + (threadIdx.x >> 7);
    int d = threadIdx.x & 127;
    int beg = rowptr[i], end = rowptr[i + 1];
    float acc = -INFINITY;
    int e = beg;
    for (; e + 2 <= end; e += 2) {
        int s0 = elist[e], s1 = elist[e + 1];
        int g0 = batch[s0], g1 = batch[s1];
        float v0 = fmaf(A1[g0 * DD + d], X[s0 * DD + d], B1[g0 * DD + d]);
        float v1 = fmaf(A1[g1 * DD + d], X[s1 * DD + d], B1[g1 * DD + d]);
        acc = fmaxf(acc, fmaxf(v0, v1));
    }
    for (; e < end; e++) {
        int s = elist[e]; int g = batch[s];
        acc = fmaxf(acc, fmaf(A1[g * DD + d], X[s * DD + d], B1[g * DD + d]));
    }
    if (end == beg) acc = 0.f;
    H[i * DD + d] = acc;
}

#define BM 128
#define LDT 72
__global__ __launch_bounds__(256) void gemm_b(
    const float* __restrict__ X, const int* __restrict__ batch,
    const float* __restrict__ A1, const float* __restrict__ B1,
    const float* __restrict__ wl, const float* __restrict__ blv, const float* __restrict__ wr,
    float* __restrict__ H)
{
    __shared__ unsigned short Ut[BM * LDT];
    __shared__ unsigned short Wt[DD * LDT];
    int i0 = blockIdx.x * BM;
    int tid = threadIdx.x;
    int lane = tid & 63, wave = tid >> 6;
    int wrow = (wave >> 1) * 64, wcol = (wave & 1) * 64;
    int m = lane & 31, hf = lane >> 5;

    f32x16 acc00, acc01, acc10, acc11;
    #pragma unroll
    for (int r = 0; r < 16; r++) { acc00[r] = 0.f; acc01[r] = 0.f; acc10[r] = 0.f; acc11[r] = 0.f; }

    for (int c = 0; c < 4; c++) {
        __syncthreads();
        for (int t = tid; t < BM * 16; t += 256) {
            int r = t >> 4, c4 = t & 15;
            int i = i0 + r; if (i >= NN) i = NN - 1;
            float4 v;
            if (c < 2) {
                v = ((const float4*)H)[i * 32 + c * 16 + c4];
            } else {
                int g = batch[i];
                float4 xv = ((const float4*)X)[i * 32 + (c - 2) * 16 + c4];
                float4 a = ((const float4*)A1)[g * 32 + (c - 2) * 16 + c4];
                float4 b = ((const float4*)B1)[g * 32 + (c - 2) * 16 + c4];
                v.x = fmaf(a.x, xv.x, b.x); v.y = fmaf(a.y, xv.y, b.y);
                v.z = fmaf(a.z, xv.z, b.z); v.w = fmaf(a.w, xv.w, b.w);
            }
            us4 o = { f2bf(v.x), f2bf(v.y), f2bf(v.z), f2bf(v.w) };
            *(us4*)&Ut[r * LDT + c4 * 4] = o;
        }
        {
            const float* Wsrc = (c < 2) ? wl : wr;
            int kb = (c & 1) * 16;
            for (int t = tid; t < DD * 16; t += 256) {
                int j = t >> 4, c4 = t & 15;
                float4 v = ((const float4*)Wsrc)[j * 32 + kb + c4];
                us4 o = { f2bf(v.x), f2bf(v.y), f2bf(v.z), f2bf(v.w) };
                *(us4*)&Wt[j * LDT + c4 * 4] = o;
            }
        }
        __syncthreads();
        #pragma unroll
        for (int kk = 0; kk < 4; kk++) {
            int kb2 = kk * 16 + hf * 8;
            bf16x8 a0 = *(const bf16x8*)&Ut[(wrow      + m) * LDT + kb2];
            bf16x8 a1 = *(const bf16x8*)&Ut[(wrow + 32 + m) * LDT + kb2];
            bf16x8 b0 = *(const bf16x8*)&Wt[(wcol      + m) * LDT + kb2];
            bf16x8 b1 = *(const bf16x8*)&Wt[(wcol + 32 + m) * LDT + kb2];
            acc00 = __builtin_amdgcn_mfma_f32_32x32x16_bf16(a0, b0, acc00, 0, 0, 0);
            acc01 = __builtin_amdgcn_mfma_f32_32x32x16_bf16(a0, b1, acc01, 0, 0, 0);
            acc10 = __builtin_amdgcn_mfma_f32_32x32x16_bf16(a1, b0, acc10, 0, 0, 0);
            acc11 = __builtin_amdgcn_mfma_f32_32x32x16_bf16(a1, b1, acc11, 0, 0, 0);
        }
    }

    int col0 = wcol + m, col1 = wcol + 32 + m;
    float bl0 = blv[col0], bl1 = blv[col1];
    #pragma unroll
    for (int reg = 0; reg < 16; reg++) {
        int rl = (reg & 3) + 8 * (reg >> 2) + 4 * hf;
        int ia = i0 + wrow + rl;
        int ib = i0 + wrow + 32 + rl;
        if (ia < NN) {
            float v0 = X[ia * DD + col0] + bl0 + acc00[reg];
            float v1 = X[ia * DD + col1] + bl1 + acc01[reg];
            H[ia * DD + col0] = v0 > 0.f ? v0 : 0.f;
            H[ia * DD + col1] = v1 > 0.f ? v1 : 0.f;
        }
        if (ib < NN) {
            float v0 = X[ib * DD + col0] + bl0 + acc10[reg];
            float v1 = X[ib * DD + col1] + bl1 + acc11[reg];
            H[ib * DD + col0] = v0 > 0.f ? v0 : 0.f;
            H[ib * DD + col1] = v1 > 0.f ? v1 : 0.f;
        }
    }
}

extern "C" void kernel_launch(void* const* d_in, const int* in_sizes, int n_in,
                              void* d_out, int out_size, void* d_ws, size_t ws_size,
                              hipStream_t stream) {
    const float* x    = (const float*)d_in[0];
    const int*   ei   = (const int*)d_in[1];
    const int*   batch= (const int*)d_in[2];
    const float* n1w  = (const float*)d_in[3];
    const float* n1b  = (const float*)d_in[4];
    const float* n1ms = (const float*)d_in[5];
    const float* n2w  = (const float*)d_in[6];
    const float* n2b  = (const float*)d_in[7];
    const float* n2ms = (const float*)d_in[8];
    const float* wl   = (const float*)d_in[9];
    const float* bl   = (const float*)d_in[10];
    const float* wr   = (const float*)d_in[11];
    float* out = (float*)d_out;

    char* w = (char*)d_ws;
    float* A1     = (float*)(w + OFF_A1);     // Sg1 -> A1
    float* B1     = (float*)(w + OFF_B1);     // Qg1 -> B1
    float* A2     = (float*)(w + OFF_A2);     // Sg2 (stays raw sums on path A)
    float* B2     = (float*)(w + OFF_B2);     // Qg2
    int*   deg    = (int*)(w + OFF_DEG);
    int*   rowptr = (int*)(w + OFF_ROWPTR);
    int*   cursor = (int*)(w + OFF_CURSOR);
    int*   bsums  = (int*)(w + OFF_BSUMS);
    int*   cnt    = (int*)(w + OFF_CNT);
    int*   elist  = (int*)(w + OFF_ELIST);
    unsigned short* wb  = (unsigned short*)(w + OFF_WB);
    unsigned short* h1b = (unsigned short*)(w + OFF_H1B);

    const int* src = ei;
    const int* dst = ei + EE;
    bool bigws = (ws_size >= WS_NEED_A);

    // zero Sg1/Qg1/Sg2/Qg2 and deg in one contiguous memset
    hipMemsetAsync(w, 0, OFF_ROWPTR, stream);

    // norm1 stats + deg (fused)
    statsdeg_kernel<<<NB_STATS + NB_EDGE, 256, 0, stream>>>(x, batch, A1, B1, dst, deg);
    finalize_kernel<<<GG + 2, 128, 0, stream>>>(batch, A1, B1, n1w, n1b, n1ms,
                                                wb, wl, wr, cnt, bigws ? 1 : 0);

    if (bigws) {
        h1bscan_kernel<<<NB_H1B + NB1024, 256, 0, stream>>>(x, batch, A1, B1, h1b, deg, bsums);
        scan3<<<NB1024, 256, 0, stream>>>(deg, bsums, rowptr, cursor);
        fill_kernel<<<NB_EDGE, 256, 0, stream>>>(src, dst, cursor, elist);

        gemm_mega<<<(NN + 63) / 64, 512, 0, stream>>>(x, h1b, batch, rowptr, elist,
                                                      wb, bl, A2, B2, out);

        apply_a<<<NB_H1B, 256, 0, stream>>>(out, batch, A2, B2, cnt, n2w, n2b, n2ms);
    } else {
        scan1<<<NB1024, 256, 0, stream>>>(deg, bsums);
        scan3<<<NB1024, 256, 0, stream>>>(deg, bsums, rowptr, cursor);
        fill_kernel<<<NB_EDGE, 256, 0, stream>>>(src, dst, cursor, elist);

        agg_b<<<NN / 2, 256, 0, stream>>>(x, batch, A1, B1, rowptr, elist, out);
        gemm_b<<<(NN + BM - 1) / BM, 256, 0, stream>>>(x, batch, A1, B1, wl, bl, wr, out);

        stats_p1<<<NB_STATS, 256, 0, stream>>>(out, batch, A2, B2);
        finalize_kernel<<<GG, 128, 0, stream>>>(batch, A2, B2, n2w, n2b, n2ms,
                                                (unsigned short*)nullptr,
                                                (const float*)nullptr, (const float*)nullptr,
                                                (int*)nullptr, 0);
        apply_b<<<NB_H1B, 256, 0, stream>>>(out, batch, A2, B2);
    }
}